// Round 1
// baseline (248.369 us; speedup 1.0000x reference)
//
#include <hip/hip_runtime.h>
#include <math.h>

#define BB 32
#define WW 100
#define FF 128
#define KS 7
#define ET 256   // 2F (temporal GAT embed)
#define EF 200   // 2W (feature GAT embed)

// ---------------- workspace layout (floats) ----------------
// x1:   0        409600   pos-encoded input (B,W,F)
// x2:   409600   409600   conv output (B,W,F)
// x3:   819200   409600   temporal GAT output (B,W,F)
// L:    1228800  819200   temporal left (B,W,256)  -> reused as Lf (B,F,200)
// R:    2048000  819200   temporal right (B,W,256) -> reused as Rf (B,F,200)
// x4:   2867200  409600   feature GAT output, (B,W,F) layout
// cos:  3276800  16384    cosine-sim matrix (F,F)
// tb:   3293184  4096     t[b,j] = sum_w fc_w[w]*x4[b,w,j]
// wt:   3297280  114688   conv weights transposed (K,I,O)
// tlwT: 3411968  65536    temp_lin_w transposed (256,256): tlwT[d][e]=tlw[e][d]
// flwT: 3477504  40000    feat_lin_w transposed (200,200)
// total: 3517504 floats = 13.4 MiB

// K0: transpose the three weight tensors for coalesced reads
__global__ void k_prep(const float* __restrict__ cw, const float* __restrict__ tlw,
                       const float* __restrict__ flw,
                       float* __restrict__ wt, float* __restrict__ tlwT,
                       float* __restrict__ flwT) {
    int id = blockIdx.x * 256 + threadIdx.x;
    if (id < KS * FF * FF) {
        // wt[k][i][o] = cw[o][i][k]
        int o = id & (FF - 1);
        int i = (id / FF) & (FF - 1);
        int k = id / (FF * FF);
        wt[id] = cw[(o * FF + i) * KS + k];
    }
    if (id < ET * ET) {
        int e = id & (ET - 1);
        int d = id / ET;
        tlwT[id] = tlw[e * ET + d];
    }
    if (id < EF * EF) {
        int e = id % EF;
        int d = id / EF;
        flwT[id] = flw[e * EF + d];
    }
}

// K1: positional encoding  x1 = x + sin(w*div_f) + cos(w*div_f)
__global__ void k_pos(const float* __restrict__ x, float* __restrict__ x1) {
    int id = blockIdx.x * 256 + threadIdx.x;
    if (id >= BB * WW * FF) return;
    int f = id & (FF - 1);
    int w = (id / FF) % WW;
    float div = __expf((float)f * (-9.210340371976184f / (float)FF));
    float arg = (float)w * div;
    x1[id] = x[id] + __sinf(arg) + __cosf(arg);
}

// K2: Conv1d over time, 'same' pad=3, relu. Time-tiled TW=10 per block.
#define TW 10
__global__ __launch_bounds__(128) void k_conv(const float* __restrict__ x1,
                                              const float* __restrict__ wt,
                                              const float* __restrict__ cb,
                                              float* __restrict__ x2) {
    int b = blockIdx.x / (WW / TW);
    int w0 = (blockIdx.x % (WW / TW)) * TW;
    int o = threadIdx.x;
    __shared__ float xs[TW + KS - 1][FF];   // rows t = w0-3 .. w0+TW+2
    for (int idx = o; idx < (TW + KS - 1) * FF; idx += 128) {
        int r = idx >> 7, f = idx & (FF - 1);
        int t = w0 - 3 + r;
        xs[r][f] = (t >= 0 && t < WW) ? x1[(b * WW + t) * FF + f] : 0.f;
    }
    __syncthreads();
    float bias = cb[o];
    float acc[TW];
#pragma unroll
    for (int t = 0; t < TW; ++t) acc[t] = bias;
    for (int i = 0; i < FF; ++i) {
        float xr[TW + KS - 1];
#pragma unroll
        for (int r = 0; r < TW + KS - 1; ++r) xr[r] = xs[r][i];
#pragma unroll
        for (int k = 0; k < KS; ++k) {
            float wv = wt[(k * FF + i) * FF + o];
#pragma unroll
            for (int t = 0; t < TW; ++t) acc[t] += xr[t + k] * wv;
        }
    }
#pragma unroll
    for (int t = 0; t < TW; ++t)
        x2[(b * WW + w0 + t) * FF + o] = fmaxf(acc[t], 0.f);
}

// K3a: temporal L/R.  L[b,i,e] = sum_d x2[b,i,d]*tlw[e,d] + tlb[e]
//                     R[b,i,e] = sum_d x2[b,i,d]*tlw[e,128+d]
#define ITT 4
__global__ __launch_bounds__(256) void k_lr_t(const float* __restrict__ x2,
                                              const float* __restrict__ tlwT,
                                              const float* __restrict__ tlb,
                                              float* __restrict__ L,
                                              float* __restrict__ R) {
    int b = blockIdx.x / (WW / ITT);
    int i0 = (blockIdx.x % (WW / ITT)) * ITT;
    int e = threadIdx.x;
    __shared__ float xs[ITT][FF];
    for (int idx = e; idx < ITT * FF; idx += 256) {
        int t = idx >> 7, d = idx & (FF - 1);
        xs[t][d] = x2[(b * WW + i0 + t) * FF + d];
    }
    __syncthreads();
    float aL[ITT] = {0, 0, 0, 0}, aR[ITT] = {0, 0, 0, 0};
    for (int d = 0; d < FF; ++d) {
        float wL = tlwT[d * ET + e];
        float wR = tlwT[(FF + d) * ET + e];
#pragma unroll
        for (int t = 0; t < ITT; ++t) {
            aL[t] += xs[t][d] * wL;
            aR[t] += xs[t][d] * wR;
        }
    }
    float lb = tlb[e];
#pragma unroll
    for (int t = 0; t < ITT; ++t) {
        L[(b * WW + i0 + t) * ET + e] = aL[t] + lb;
        R[(b * WW + i0 + t) * ET + e] = aR[t];
    }
}

// K3b: temporal attention: scores, softmax over j, out = tanh(att @ x2)
__global__ __launch_bounds__(128) void k_att_t(const float* __restrict__ L,
                                               const float* __restrict__ R,
                                               const float* __restrict__ ta,
                                               const float* __restrict__ tbias,
                                               const float* __restrict__ x2,
                                               float* __restrict__ x3) {
    int b = blockIdx.x / WW;
    int i = blockIdx.x % WW;
    int tid = threadIdx.x;
    __shared__ float Ls[ET], as_[ET], att[WW], red[128];
    Ls[tid] = L[(b * WW + i) * ET + tid];
    Ls[tid + 128] = L[(b * WW + i) * ET + tid + 128];
    as_[tid] = ta[tid];
    as_[tid + 128] = ta[tid + 128];
    __syncthreads();
    float ej = -1e30f;
    if (tid < WW) {
        const float* Rr = R + (b * WW + tid) * ET;
        float s = 0.f;
        for (int e = 0; e < ET; ++e) {
            float v = Ls[e] + Rr[e];
            v = (v >= 0.f) ? v : 0.2f * v;
            s += v * as_[e];
        }
        ej = s + tbias[i * WW + tid];
    }
    // max-reduce
    red[tid] = ej;
    __syncthreads();
    for (int off = 64; off > 0; off >>= 1) {
        if (tid < off) red[tid] = fmaxf(red[tid], red[tid + off]);
        __syncthreads();
    }
    float mx = red[0];
    __syncthreads();
    float p = (tid < WW) ? __expf(ej - mx) : 0.f;
    red[tid] = p;
    __syncthreads();
    for (int off = 64; off > 0; off >>= 1) {
        if (tid < off) red[tid] += red[tid + off];
        __syncthreads();
    }
    float inv = 1.f / red[0];
    if (tid < WW) att[tid] = p * inv;
    __syncthreads();
    // out: thread = d
    float acc = 0.f;
    for (int j = 0; j < WW; ++j) acc += att[j] * x2[(b * WW + j) * FF + tid];
    x3[(b * WW + i) * FF + tid] = tanhf(acc);
}

// K4a: feature L/R over transposed nodes. vf[b,f,d] = x3[b,d,f], d<100
__global__ __launch_bounds__(256) void k_lr_f(const float* __restrict__ x3,
                                              const float* __restrict__ flwT,
                                              const float* __restrict__ flb,
                                              float* __restrict__ Lf,
                                              float* __restrict__ Rf) {
    int b = blockIdx.x / (FF / ITT);
    int f0 = (blockIdx.x % (FF / ITT)) * ITT;
    int e = threadIdx.x;
    __shared__ float vs[ITT][WW];
    for (int idx = e; idx < ITT * WW; idx += 256) {
        int t = idx / WW, d = idx % WW;
        vs[t][d] = x3[(b * WW + d) * FF + f0 + t];
    }
    __syncthreads();
    if (e < EF) {
        float aL[ITT] = {0, 0, 0, 0}, aR[ITT] = {0, 0, 0, 0};
        for (int d = 0; d < WW; ++d) {
            float wL = flwT[d * EF + e];
            float wR = flwT[(WW + d) * EF + e];
#pragma unroll
            for (int t = 0; t < ITT; ++t) {
                aL[t] += vs[t][d] * wL;
                aR[t] += vs[t][d] * wR;
            }
        }
        float lb = flb[e];
#pragma unroll
        for (int t = 0; t < ITT; ++t) {
            Lf[(b * FF + f0 + t) * EF + e] = aL[t] + lb;
            Rf[(b * FF + f0 + t) * EF + e] = aR[t];
        }
    }
}

// K4b: feature attention. nodes = features (128), out dim = time (100).
__global__ __launch_bounds__(128) void k_att_f(const float* __restrict__ Lf,
                                               const float* __restrict__ Rf,
                                               const float* __restrict__ fa,
                                               const float* __restrict__ fbias,
                                               const float* __restrict__ x3,
                                               float* __restrict__ x4) {
    int b = blockIdx.x / FF;
    int fi = blockIdx.x % FF;
    int tid = threadIdx.x;
    __shared__ float Ls[EF], as_[EF], att[FF], red[128];
    for (int k = tid; k < EF; k += 128) {
        Ls[k] = Lf[(b * FF + fi) * EF + k];
        as_[k] = fa[k];
    }
    __syncthreads();
    float ej;
    {
        const float* Rr = Rf + (b * FF + tid) * EF;
        float s = 0.f;
        for (int e = 0; e < EF; ++e) {
            float v = Ls[e] + Rr[e];
            v = (v >= 0.f) ? v : 0.2f * v;
            s += v * as_[e];
        }
        ej = s + fbias[fi * FF + tid];
    }
    red[tid] = ej;
    __syncthreads();
    for (int off = 64; off > 0; off >>= 1) {
        if (tid < off) red[tid] = fmaxf(red[tid], red[tid + off]);
        __syncthreads();
    }
    float mx = red[0];
    __syncthreads();
    float p = __expf(ej - mx);
    red[tid] = p;
    __syncthreads();
    for (int off = 64; off > 0; off >>= 1) {
        if (tid < off) red[tid] += red[tid + off];
        __syncthreads();
    }
    float inv = 1.f / red[0];
    att[tid] = p * inv;
    __syncthreads();
    if (tid < WW) {
        float acc = 0.f;
        const float* xr = x3 + (b * WW + tid) * FF;
        for (int j = 0; j < FF; ++j) acc += att[j] * xr[j];
        x4[(b * WW + tid) * FF + fi] = tanhf(acc);
    }
}

// K5: cosine similarity matrix from emb (F,8)
__global__ void k_cos(const float* __restrict__ emb, float* __restrict__ cosm) {
    int id = blockIdx.x * 256 + threadIdx.x;
    if (id >= FF * FF) return;
    int i = id / FF, j = id & (FF - 1);
    float s = 0.f, ni = 0.f, nj = 0.f;
#pragma unroll
    for (int k = 0; k < 8; ++k) {
        float a = emb[i * 8 + k], c = emb[j * 8 + k];
        s += a * c;
        ni += a * a;
        nj += c * c;
    }
    cosm[id] = s * rsqrtf(ni) * rsqrtf(nj);
}

// K6a: t[b,j] = sum_w fc_w[w] * x4[b,w,j]
__global__ void k_t(const float* __restrict__ x4, const float* __restrict__ fcw,
                    float* __restrict__ tb) {
    int id = blockIdx.x * 256 + threadIdx.x;
    if (id >= BB * FF) return;
    int b = id / FF, j = id & (FF - 1);
    float s = 0.f;
    for (int w = 0; w < WW; ++w) s += fcw[w] * x4[(b * WW + w) * FF + j];
    tb[id] = s;
}

// K6b: out[b,f] = tanh(sum_j cos[f,j] * t[b,j] + fc_b)
__global__ void k_out(const float* __restrict__ tb, const float* __restrict__ cosm,
                      const float* __restrict__ fcb, float* __restrict__ out) {
    int id = blockIdx.x * 256 + threadIdx.x;
    if (id >= BB * FF) return;
    int b = id / FF, f = id & (FF - 1);
    float s = fcb[0];
    for (int j = 0; j < FF; ++j) s += cosm[f * FF + j] * tb[b * FF + j];
    out[id] = tanhf(s);
}

extern "C" void kernel_launch(void* const* d_in, const int* in_sizes, int n_in,
                              void* d_out, int out_size, void* d_ws, size_t ws_size,
                              hipStream_t stream) {
    const float* x     = (const float*)d_in[0];
    const float* cw    = (const float*)d_in[1];
    const float* cb    = (const float*)d_in[2];
    const float* tlw   = (const float*)d_in[3];
    const float* tlb   = (const float*)d_in[4];
    const float* ta    = (const float*)d_in[5];
    const float* tbias = (const float*)d_in[6];
    const float* flw   = (const float*)d_in[7];
    const float* flb   = (const float*)d_in[8];
    const float* fa    = (const float*)d_in[9];
    const float* fbias = (const float*)d_in[10];
    const float* emb   = (const float*)d_in[11];
    const float* fcw   = (const float*)d_in[12];
    const float* fcb   = (const float*)d_in[13];
    float* out = (float*)d_out;
    float* ws = (float*)d_ws;

    float* x1   = ws + 0;
    float* x2   = ws + 409600;
    float* x3   = ws + 819200;
    float* L    = ws + 1228800;   // reused as Lf
    float* R    = ws + 2048000;   // reused as Rf
    float* x4   = ws + 2867200;
    float* cosm = ws + 3276800;
    float* tb   = ws + 3293184;
    float* wt   = ws + 3297280;
    float* tlwT = ws + 3411968;
    float* flwT = ws + 3477504;

    k_prep<<<448, 256, 0, stream>>>(cw, tlw, flw, wt, tlwT, flwT);
    k_pos<<<1600, 256, 0, stream>>>(x, x1);
    k_conv<<<BB * (WW / TW), 128, 0, stream>>>(x1, wt, cb, x2);
    k_lr_t<<<BB * (WW / ITT), 256, 0, stream>>>(x2, tlwT, tlb, L, R);
    k_att_t<<<BB * WW, 128, 0, stream>>>(L, R, ta, tbias, x2, x3);
    k_lr_f<<<BB * (FF / ITT), 256, 0, stream>>>(x3, flwT, flb, L, R);
    k_att_f<<<BB * FF, 128, 0, stream>>>(L, R, fa, fbias, x3, x4);
    k_cos<<<64, 256, 0, stream>>>(emb, cosm);
    k_t<<<16, 256, 0, stream>>>(x4, fcw, tb);
    k_out<<<16, 256, 0, stream>>>(tb, cosm, fcb, out);
}

// Round 2
// 173.237 us; speedup vs baseline: 1.4337x; 1.4337x over previous
//
#include <hip/hip_runtime.h>
#include <math.h>

#define BB 32
#define WW 100
#define FF 128
#define KS 7
#define ET 256   // 2F (temporal GAT embed)
#define EF 200   // 2W (feature GAT embed)

// ---------------- workspace layout (floats) ----------------
// x1:   0        409600   pos-encoded input (B,W,F)
// x2:   409600   409600   conv output (B,W,F)
// x3T:  819200   409600   temporal GAT output, TRANSPOSED (B,F,W)
// L:    1228800  819200   temporal left (B,W,256)  -> reused as Lf (B,F,200)
// Rt:   2048000  819200   temporal right TRANSPOSED (B,256,W) -> reused as RfT (B,200,F)
// x4T:  2867200  409600   feature GAT output, TRANSPOSED (B,F,W)
// cos:  3276800  16384    cosine-sim matrix (F,F)
// wt:   3297280  114688   conv weights transposed (K,I,O)
// tlwT: 3411968  65536    temp_lin_w transposed (256,256)
// flwT: 3477504  40000    feat_lin_w transposed (200,200)

// K0: transpose the three weight tensors for coalesced reads
__global__ void k_prep(const float* __restrict__ cw, const float* __restrict__ tlw,
                       const float* __restrict__ flw,
                       float* __restrict__ wt, float* __restrict__ tlwT,
                       float* __restrict__ flwT) {
    int id = blockIdx.x * 256 + threadIdx.x;
    if (id < KS * FF * FF) {
        int o = id & (FF - 1);
        int i = (id / FF) & (FF - 1);
        int k = id / (FF * FF);
        wt[id] = cw[(o * FF + i) * KS + k];
    }
    if (id < ET * ET) {
        int e = id & (ET - 1);
        int d = id / ET;
        tlwT[id] = tlw[e * ET + d];
    }
    if (id < EF * EF) {
        int e = id % EF;
        int d = id / EF;
        flwT[id] = flw[e * EF + d];
    }
}

// K1: positional encoding
__global__ void k_pos(const float* __restrict__ x, float* __restrict__ x1) {
    int id = blockIdx.x * 256 + threadIdx.x;
    if (id >= BB * WW * FF) return;
    int f = id & (FF - 1);
    int w = (id / FF) % WW;
    float div = __expf((float)f * (-9.210340371976184f / (float)FF));
    float arg = (float)w * div;
    x1[id] = x[id] + __sinf(arg) + __cosf(arg);
}

// K2: Conv1d over time, 'same' pad=3, relu. Time-tiled TW=10 per block.
#define TW 10
__global__ __launch_bounds__(128) void k_conv(const float* __restrict__ x1,
                                              const float* __restrict__ wt,
                                              const float* __restrict__ cb,
                                              float* __restrict__ x2) {
    int b = blockIdx.x / (WW / TW);
    int w0 = (blockIdx.x % (WW / TW)) * TW;
    int o = threadIdx.x;
    __shared__ float xs[TW + KS - 1][FF];
    for (int idx = o; idx < (TW + KS - 1) * FF; idx += 128) {
        int r = idx >> 7, f = idx & (FF - 1);
        int t = w0 - 3 + r;
        xs[r][f] = (t >= 0 && t < WW) ? x1[(b * WW + t) * FF + f] : 0.f;
    }
    __syncthreads();
    float bias = cb[o];
    float acc[TW];
#pragma unroll
    for (int t = 0; t < TW; ++t) acc[t] = bias;
    for (int i = 0; i < FF; ++i) {
        float xr[TW + KS - 1];
#pragma unroll
        for (int r = 0; r < TW + KS - 1; ++r) xr[r] = xs[r][i];
#pragma unroll
        for (int k = 0; k < KS; ++k) {
            float wv = wt[(k * FF + i) * FF + o];
#pragma unroll
            for (int t = 0; t < TW; ++t) acc[t] += xr[t + k] * wv;
        }
    }
#pragma unroll
    for (int t = 0; t < TW; ++t)
        x2[(b * WW + w0 + t) * FF + o] = fmaxf(acc[t], 0.f);
}

// K3a: temporal L/R. L row-major (B,W,ET); R transposed to Rt (B,ET,W).
#define ITT 4
__global__ __launch_bounds__(256) void k_lr_t(const float* __restrict__ x2,
                                              const float* __restrict__ tlwT,
                                              const float* __restrict__ tlb,
                                              float* __restrict__ L,
                                              float* __restrict__ Rt) {
    int b = blockIdx.x / (WW / ITT);
    int i0 = (blockIdx.x % (WW / ITT)) * ITT;
    int e = threadIdx.x;
    __shared__ float xs[ITT][FF];
    for (int idx = e; idx < ITT * FF; idx += 256) {
        int t = idx >> 7, d = idx & (FF - 1);
        xs[t][d] = x2[(b * WW + i0 + t) * FF + d];
    }
    __syncthreads();
    float aL[ITT] = {0, 0, 0, 0}, aR[ITT] = {0, 0, 0, 0};
    for (int d = 0; d < FF; ++d) {
        float wL = tlwT[d * ET + e];
        float wR = tlwT[(FF + d) * ET + e];
#pragma unroll
        for (int t = 0; t < ITT; ++t) {
            aL[t] += xs[t][d] * wL;
            aR[t] += xs[t][d] * wR;
        }
    }
    float lb = tlb[e];
#pragma unroll
    for (int t = 0; t < ITT; ++t)
        L[(b * WW + i0 + t) * ET + e] = aL[t] + lb;
    float4 rv = make_float4(aR[0], aR[1], aR[2], aR[3]);
    *(float4*)&Rt[(b * ET + e) * WW + i0] = rv;
}

// K3b: temporal attention. Rt reads coalesced; writes x3T (B,F,W).
__global__ __launch_bounds__(128) void k_att_t(const float* __restrict__ L,
                                               const float* __restrict__ Rt,
                                               const float* __restrict__ ta,
                                               const float* __restrict__ tbias,
                                               const float* __restrict__ x2,
                                               float* __restrict__ x3T) {
    int b = blockIdx.x / WW;
    int i = blockIdx.x % WW;
    int tid = threadIdx.x;
    __shared__ float Ls[ET], as_[ET], att[WW], red[128];
    Ls[tid] = L[(b * WW + i) * ET + tid];
    Ls[tid + 128] = L[(b * WW + i) * ET + tid + 128];
    as_[tid] = ta[tid];
    as_[tid + 128] = ta[tid + 128];
    __syncthreads();
    float ej = -1e30f;
    if (tid < WW) {
        float s = 0.f;
        for (int e = 0; e < ET; ++e) {
            float v = Ls[e] + Rt[(b * ET + e) * WW + tid];
            v = (v >= 0.f) ? v : 0.2f * v;
            s += v * as_[e];
        }
        ej = s + tbias[i * WW + tid];
    }
    red[tid] = ej;
    __syncthreads();
    for (int off = 64; off > 0; off >>= 1) {
        if (tid < off) red[tid] = fmaxf(red[tid], red[tid + off]);
        __syncthreads();
    }
    float mx = red[0];
    __syncthreads();
    float p = (tid < WW) ? __expf(ej - mx) : 0.f;
    red[tid] = p;
    __syncthreads();
    for (int off = 64; off > 0; off >>= 1) {
        if (tid < off) red[tid] += red[tid + off];
        __syncthreads();
    }
    float inv = 1.f / red[0];
    if (tid < WW) att[tid] = p * inv;
    __syncthreads();
    float acc = 0.f;
    for (int j = 0; j < WW; ++j) acc += att[j] * x2[(b * WW + j) * FF + tid];
    x3T[(b * FF + tid) * WW + i] = tanhf(acc);
}

// K4a: feature L/R. Reads x3T coalesced. Lf row-major (B,F,200); RfT (B,200,F).
__global__ __launch_bounds__(256) void k_lr_f(const float* __restrict__ x3T,
                                              const float* __restrict__ flwT,
                                              const float* __restrict__ flb,
                                              float* __restrict__ Lf,
                                              float* __restrict__ RfT) {
    int b = blockIdx.x / (FF / ITT);
    int f0 = (blockIdx.x % (FF / ITT)) * ITT;
    int e = threadIdx.x;
    __shared__ float vs[ITT][WW];
    for (int idx = e; idx < ITT * WW; idx += 256) {
        int t = idx / WW, d = idx % WW;
        vs[t][d] = x3T[(b * FF + f0 + t) * WW + d];
    }
    __syncthreads();
    if (e < EF) {
        float aL[ITT] = {0, 0, 0, 0}, aR[ITT] = {0, 0, 0, 0};
        for (int d = 0; d < WW; ++d) {
            float wL = flwT[d * EF + e];
            float wR = flwT[(WW + d) * EF + e];
#pragma unroll
            for (int t = 0; t < ITT; ++t) {
                aL[t] += vs[t][d] * wL;
                aR[t] += vs[t][d] * wR;
            }
        }
        float lb = flb[e];
#pragma unroll
        for (int t = 0; t < ITT; ++t)
            Lf[(b * FF + f0 + t) * EF + e] = aL[t] + lb;
        float4 rv = make_float4(aR[0], aR[1], aR[2], aR[3]);
        *(float4*)&RfT[(b * EF + e) * FF + f0] = rv;
    }
}

// K4b: feature attention. RfT + x3T reads coalesced; writes x4T (B,F,W) coalesced.
__global__ __launch_bounds__(128) void k_att_f(const float* __restrict__ Lf,
                                               const float* __restrict__ RfT,
                                               const float* __restrict__ fa,
                                               const float* __restrict__ fbias,
                                               const float* __restrict__ x3T,
                                               float* __restrict__ x4T) {
    int b = blockIdx.x / FF;
    int fi = blockIdx.x % FF;
    int tid = threadIdx.x;
    __shared__ float Ls[EF], as_[EF], att[FF], red[128];
    for (int k = tid; k < EF; k += 128) {
        Ls[k] = Lf[(b * FF + fi) * EF + k];
        as_[k] = fa[k];
    }
    __syncthreads();
    float s = 0.f;
    for (int e = 0; e < EF; ++e) {
        float v = Ls[e] + RfT[(b * EF + e) * FF + tid];
        v = (v >= 0.f) ? v : 0.2f * v;
        s += v * as_[e];
    }
    float ej = s + fbias[fi * FF + tid];
    red[tid] = ej;
    __syncthreads();
    for (int off = 64; off > 0; off >>= 1) {
        if (tid < off) red[tid] = fmaxf(red[tid], red[tid + off]);
        __syncthreads();
    }
    float mx = red[0];
    __syncthreads();
    float p = __expf(ej - mx);
    red[tid] = p;
    __syncthreads();
    for (int off = 64; off > 0; off >>= 1) {
        if (tid < off) red[tid] += red[tid + off];
        __syncthreads();
    }
    float inv = 1.f / red[0];
    att[tid] = p * inv;
    __syncthreads();
    if (tid < WW) {
        float acc = 0.f;
        for (int j = 0; j < FF; ++j) acc += att[j] * x3T[(b * FF + j) * WW + tid];
        x4T[(b * FF + fi) * WW + tid] = tanhf(acc);
    }
}

// K5: cosine similarity matrix from emb (F,8)
__global__ void k_cos(const float* __restrict__ emb, float* __restrict__ cosm) {
    int id = blockIdx.x * 256 + threadIdx.x;
    if (id >= FF * FF) return;
    int i = id / FF, j = id & (FF - 1);
    float s = 0.f, ni = 0.f, nj = 0.f;
#pragma unroll
    for (int k = 0; k < 8; ++k) {
        float a = emb[i * 8 + k], c = emb[j * 8 + k];
        s += a * c;
        ni += a * a;
        nj += c * c;
    }
    cosm[id] = s * rsqrtf(ni) * rsqrtf(nj);
}

// K6: fused forecast. t[b,j] = sum_w fcw[w]*x4T[b,j,w];
//     out[b,f] = tanh(sum_j cos[f,j]*t[b,j] + fc_b). One block per b.
__global__ __launch_bounds__(128) void k_fc(const float* __restrict__ x4T,
                                            const float* __restrict__ fcw,
                                            const float* __restrict__ cosm,
                                            const float* __restrict__ fcb,
                                            float* __restrict__ out) {
    int b = blockIdx.x;
    int tid = threadIdx.x;
    __shared__ float tj[FF];
    {
        float s = 0.f;
        const float* xr = x4T + (b * FF + tid) * WW;
        for (int w = 0; w < WW; ++w) s += fcw[w] * xr[w];
        tj[tid] = s;
    }
    __syncthreads();
    float s = fcb[0];
    for (int j = 0; j < FF; ++j) s += cosm[tid * FF + j] * tj[j];
    out[b * FF + tid] = tanhf(s);
}

extern "C" void kernel_launch(void* const* d_in, const int* in_sizes, int n_in,
                              void* d_out, int out_size, void* d_ws, size_t ws_size,
                              hipStream_t stream) {
    const float* x     = (const float*)d_in[0];
    const float* cw    = (const float*)d_in[1];
    const float* cb    = (const float*)d_in[2];
    const float* tlw   = (const float*)d_in[3];
    const float* tlb   = (const float*)d_in[4];
    const float* ta    = (const float*)d_in[5];
    const float* tbias = (const float*)d_in[6];
    const float* flw   = (const float*)d_in[7];
    const float* flb   = (const float*)d_in[8];
    const float* fa    = (const float*)d_in[9];
    const float* fbias = (const float*)d_in[10];
    const float* emb   = (const float*)d_in[11];
    const float* fcw   = (const float*)d_in[12];
    const float* fcb   = (const float*)d_in[13];
    float* out = (float*)d_out;
    float* ws = (float*)d_ws;

    float* x1   = ws + 0;
    float* x2   = ws + 409600;
    float* x3T  = ws + 819200;
    float* L    = ws + 1228800;   // reused as Lf
    float* Rt   = ws + 2048000;   // reused as RfT
    float* x4T  = ws + 2867200;
    float* cosm = ws + 3276800;
    float* wt   = ws + 3297280;
    float* tlwT = ws + 3411968;
    float* flwT = ws + 3477504;

    k_prep<<<448, 256, 0, stream>>>(cw, tlw, flw, wt, tlwT, flwT);
    k_pos<<<1600, 256, 0, stream>>>(x, x1);
    k_conv<<<BB * (WW / TW), 128, 0, stream>>>(x1, wt, cb, x2);
    k_lr_t<<<BB * (WW / ITT), 256, 0, stream>>>(x2, tlwT, tlb, L, Rt);
    k_att_t<<<BB * WW, 128, 0, stream>>>(L, Rt, ta, tbias, x2, x3T);
    k_lr_f<<<BB * (FF / ITT), 256, 0, stream>>>(x3T, flwT, flb, L, Rt);
    k_att_f<<<BB * FF, 128, 0, stream>>>(L, Rt, fa, fbias, x3T, x4T);
    k_cos<<<64, 256, 0, stream>>>(emb, cosm);
    k_fc<<<BB, 128, 0, stream>>>(x4T, fcw, cosm, fcb, out);
}

// Round 3
// 155.216 us; speedup vs baseline: 1.6001x; 1.1161x over previous
//
#include <hip/hip_runtime.h>
#include <math.h>

#define BB 32
#define WW 100
#define FF 128
#define KS 7
#define ET 256   // 2F (temporal GAT embed)
#define EF 200   // 2W (feature GAT embed)

// ---------------- workspace layout (floats) ----------------
// x2:   409600   409600   conv output (B,W,F)
// x3T:  819200   409600   temporal GAT output, TRANSPOSED (B,F,W)
// L:    1228800  819200   temporal left (B,W,256)  -> reused as Lf (B,F,200)
// Rt:   2048000  819200   temporal right TRANSPOSED (B,256,W) -> reused as RfT (B,200,F)
// x4T:  2867200  409600   feature GAT output, TRANSPOSED (B,F,W)
// wt:   3297280  114688   conv weights transposed (I,K,O)
// tlwT: 3411968  65536    temp_lin_w transposed (256,256)
// flwT: 3477504  40000    feat_lin_w transposed (200,200)

// K0: transpose the three weight tensors for coalesced reads
__global__ void k_prep(const float* __restrict__ cw, const float* __restrict__ tlw,
                       const float* __restrict__ flw,
                       float* __restrict__ wt, float* __restrict__ tlwT,
                       float* __restrict__ flwT) {
    int id = blockIdx.x * 256 + threadIdx.x;
    if (id < KS * FF * FF) {
        // wt[i][k][o] = cw[o][i][k]
        int o = id & (FF - 1);
        int r = id >> 7;
        int k = r % KS;
        int i = r / KS;
        wt[id] = cw[(o * FF + i) * KS + k];
    }
    if (id < ET * ET) {
        int e = id & (ET - 1);
        int d = id / ET;
        tlwT[id] = tlw[e * ET + d];
    }
    if (id < EF * EF) {
        int e = id % EF;
        int d = id / EF;
        flwT[id] = flw[e * EF + d];
    }
}

// K2: Conv1d over time, 'same' pad=3, relu. Pos-encode fused into staging.
// Block: 512 threads = (o:128) x (h:4). TW=12 time steps/block, NT=3 per thread.
#define TW 12
#define NT 3
#define NROW (TW + KS - 1)   // 18 staged rows
__global__ __launch_bounds__(512) void k_conv(const float* __restrict__ x,
                                              const float* __restrict__ wt,
                                              const float* __restrict__ cb,
                                              float* __restrict__ x2) {
    int ntile = (WW + TW - 1) / TW;  // 9
    int b = blockIdx.x / ntile;
    int w0 = (blockIdx.x % ntile) * TW;
    int o = threadIdx.x & (FF - 1);
    int h = threadIdx.x >> 7;        // 0..3, wave-uniform
    __shared__ float xs[NROW][FF];
    for (int idx = threadIdx.x; idx < NROW * FF; idx += 512) {
        int r = idx >> 7, f = idx & (FF - 1);
        int t = w0 - 3 + r;
        float v = 0.f;
        if (t >= 0 && t < WW) {
            float div = __expf((float)f * (-9.210340371976184f / (float)FF));
            float arg = (float)t * div;
            v = x[(b * WW + t) * FF + f] + __sinf(arg) + __cosf(arg);
        }
        xs[r][f] = v;
    }
    __syncthreads();
    float bias = cb[o];
    float acc[NT] = {bias, bias, bias};
    int t0 = h * NT;  // local time base (wave-uniform)
#pragma unroll 2
    for (int i = 0; i < FF; i += 4) {
        float xr[NT + KS - 1][4];   // rows t0..t0+8, 4 consecutive i
#pragma unroll
        for (int r = 0; r < NT + KS - 1; ++r)
            *(float4*)xr[r] = *(const float4*)&xs[t0 + r][i];
#pragma unroll
        for (int q = 0; q < 4; ++q) {
#pragma unroll
            for (int k = 0; k < KS; ++k) {
                float wv = wt[((i + q) * KS + k) * FF + o];
#pragma unroll
                for (int t = 0; t < NT; ++t) acc[t] += xr[t + k][q] * wv;
            }
        }
    }
#pragma unroll
    for (int t = 0; t < NT; ++t) {
        int w = w0 + t0 + t;
        if (w < WW) x2[(b * WW + w) * FF + o] = fmaxf(acc[t], 0.f);
    }
}

// K3a: temporal L/R. L row-major (B,W,ET); R transposed to Rt (B,ET,W).
#define ITT 4
__global__ __launch_bounds__(256) void k_lr_t(const float* __restrict__ x2,
                                              const float* __restrict__ tlwT,
                                              const float* __restrict__ tlb,
                                              float* __restrict__ L,
                                              float* __restrict__ Rt) {
    int b = blockIdx.x / (WW / ITT);
    int i0 = (blockIdx.x % (WW / ITT)) * ITT;
    int e = threadIdx.x;
    __shared__ float xs[ITT][FF];
    for (int idx = e; idx < ITT * FF; idx += 256) {
        int t = idx >> 7, d = idx & (FF - 1);
        xs[t][d] = x2[(b * WW + i0 + t) * FF + d];
    }
    __syncthreads();
    float aL[ITT] = {0, 0, 0, 0}, aR[ITT] = {0, 0, 0, 0};
    for (int d = 0; d < FF; ++d) {
        float wL = tlwT[d * ET + e];
        float wR = tlwT[(FF + d) * ET + e];
#pragma unroll
        for (int t = 0; t < ITT; ++t) {
            aL[t] += xs[t][d] * wL;
            aR[t] += xs[t][d] * wR;
        }
    }
    float lb = tlb[e];
#pragma unroll
    for (int t = 0; t < ITT; ++t)
        L[(b * WW + i0 + t) * ET + e] = aL[t] + lb;
    float4 rv = make_float4(aR[0], aR[1], aR[2], aR[3]);
    *(float4*)&Rt[(b * ET + e) * WW + i0] = rv;
}

// K3b: temporal attention. Rt reads coalesced; writes x3T (B,F,W).
__global__ __launch_bounds__(128) void k_att_t(const float* __restrict__ L,
                                               const float* __restrict__ Rt,
                                               const float* __restrict__ ta,
                                               const float* __restrict__ tbias,
                                               const float* __restrict__ x2,
                                               float* __restrict__ x3T) {
    int b = blockIdx.x / WW;
    int i = blockIdx.x % WW;
    int tid = threadIdx.x;
    __shared__ float Ls[ET], as_[ET], att[WW], red[128];
    Ls[tid] = L[(b * WW + i) * ET + tid];
    Ls[tid + 128] = L[(b * WW + i) * ET + tid + 128];
    as_[tid] = ta[tid];
    as_[tid + 128] = ta[tid + 128];
    __syncthreads();
    float ej = -1e30f;
    if (tid < WW) {
        float s = 0.f;
        for (int e = 0; e < ET; ++e) {
            float v = Ls[e] + Rt[(b * ET + e) * WW + tid];
            v = (v >= 0.f) ? v : 0.2f * v;
            s += v * as_[e];
        }
        ej = s + tbias[i * WW + tid];
    }
    red[tid] = ej;
    __syncthreads();
    for (int off = 64; off > 0; off >>= 1) {
        if (tid < off) red[tid] = fmaxf(red[tid], red[tid + off]);
        __syncthreads();
    }
    float mx = red[0];
    __syncthreads();
    float p = (tid < WW) ? __expf(ej - mx) : 0.f;
    red[tid] = p;
    __syncthreads();
    for (int off = 64; off > 0; off >>= 1) {
        if (tid < off) red[tid] += red[tid + off];
        __syncthreads();
    }
    float inv = 1.f / red[0];
    if (tid < WW) att[tid] = p * inv;
    __syncthreads();
    float acc = 0.f;
    for (int j = 0; j < WW; ++j) acc += att[j] * x2[(b * WW + j) * FF + tid];
    x3T[(b * FF + tid) * WW + i] = tanhf(acc);
}

// K4a: feature L/R. Reads x3T coalesced. Lf row-major (B,F,200); RfT (B,200,F).
__global__ __launch_bounds__(256) void k_lr_f(const float* __restrict__ x3T,
                                              const float* __restrict__ flwT,
                                              const float* __restrict__ flb,
                                              float* __restrict__ Lf,
                                              float* __restrict__ RfT) {
    int b = blockIdx.x / (FF / ITT);
    int f0 = (blockIdx.x % (FF / ITT)) * ITT;
    int e = threadIdx.x;
    __shared__ float vs[ITT][WW];
    for (int idx = e; idx < ITT * WW; idx += 256) {
        int t = idx / WW, d = idx % WW;
        vs[t][d] = x3T[(b * FF + f0 + t) * WW + d];
    }
    __syncthreads();
    if (e < EF) {
        float aL[ITT] = {0, 0, 0, 0}, aR[ITT] = {0, 0, 0, 0};
        for (int d = 0; d < WW; ++d) {
            float wL = flwT[d * EF + e];
            float wR = flwT[(WW + d) * EF + e];
#pragma unroll
            for (int t = 0; t < ITT; ++t) {
                aL[t] += vs[t][d] * wL;
                aR[t] += vs[t][d] * wR;
            }
        }
        float lb = flb[e];
#pragma unroll
        for (int t = 0; t < ITT; ++t)
            Lf[(b * FF + f0 + t) * EF + e] = aL[t] + lb;
        float4 rv = make_float4(aR[0], aR[1], aR[2], aR[3]);
        *(float4*)&RfT[(b * EF + e) * FF + f0] = rv;
    }
}

// K4b: feature attention. RfT + x3T reads coalesced; writes x4T (B,F,W).
__global__ __launch_bounds__(128) void k_att_f(const float* __restrict__ Lf,
                                               const float* __restrict__ RfT,
                                               const float* __restrict__ fa,
                                               const float* __restrict__ fbias,
                                               const float* __restrict__ x3T,
                                               float* __restrict__ x4T) {
    int b = blockIdx.x / FF;
    int fi = blockIdx.x % FF;
    int tid = threadIdx.x;
    __shared__ float Ls[EF], as_[EF], att[FF], red[128];
    for (int k = tid; k < EF; k += 128) {
        Ls[k] = Lf[(b * FF + fi) * EF + k];
        as_[k] = fa[k];
    }
    __syncthreads();
    float s = 0.f;
    for (int e = 0; e < EF; ++e) {
        float v = Ls[e] + RfT[(b * EF + e) * FF + tid];
        v = (v >= 0.f) ? v : 0.2f * v;
        s += v * as_[e];
    }
    float ej = s + fbias[fi * FF + tid];
    red[tid] = ej;
    __syncthreads();
    for (int off = 64; off > 0; off >>= 1) {
        if (tid < off) red[tid] = fmaxf(red[tid], red[tid + off]);
        __syncthreads();
    }
    float mx = red[0];
    __syncthreads();
    float p = __expf(ej - mx);
    red[tid] = p;
    __syncthreads();
    for (int off = 64; off > 0; off >>= 1) {
        if (tid < off) red[tid] += red[tid + off];
        __syncthreads();
    }
    float inv = 1.f / red[0];
    att[tid] = p * inv;
    __syncthreads();
    if (tid < WW) {
        float acc = 0.f;
        for (int j = 0; j < FF; ++j) acc += att[j] * x3T[(b * FF + j) * WW + tid];
        x4T[(b * FF + fi) * WW + tid] = tanhf(acc);
    }
}

// K6: fused cosine-matrix + forecast. One block per b, 128 threads.
// t[b,j] = sum_w fcw[w]*x4T[b,j,w];  out[b,f] = tanh(sum_j cos[f,j]*t[b,j]+fcb)
__global__ __launch_bounds__(128) void k_fc(const float* __restrict__ x4T,
                                            const float* __restrict__ fcw,
                                            const float* __restrict__ emb,
                                            const float* __restrict__ fcb,
                                            float* __restrict__ out) {
    int b = blockIdx.x;
    int tid = threadIdx.x;
    __shared__ float tj[FF];
    __shared__ float en[FF][9];   // normalized emb rows, padded
    {
        float4 e0 = *(const float4*)&emb[tid * 8];
        float4 e1 = *(const float4*)&emb[tid * 8 + 4];
        float n = e0.x * e0.x + e0.y * e0.y + e0.z * e0.z + e0.w * e0.w +
                  e1.x * e1.x + e1.y * e1.y + e1.z * e1.z + e1.w * e1.w;
        float rin = rsqrtf(n);
        en[tid][0] = e0.x * rin; en[tid][1] = e0.y * rin;
        en[tid][2] = e0.z * rin; en[tid][3] = e0.w * rin;
        en[tid][4] = e1.x * rin; en[tid][5] = e1.y * rin;
        en[tid][6] = e1.z * rin; en[tid][7] = e1.w * rin;
    }
    {
        float s = 0.f;
        const float* xr = x4T + (b * FF + tid) * WW;
        for (int w = 0; w < WW; ++w) s += fcw[w] * xr[w];
        tj[tid] = s;
    }
    __syncthreads();
    float er[8];
#pragma unroll
    for (int k = 0; k < 8; ++k) er[k] = en[tid][k];
    float acc = fcb[0];
    for (int j = 0; j < FF; ++j) {
        float d = 0.f;
#pragma unroll
        for (int k = 0; k < 8; ++k) d += er[k] * en[j][k];
        acc += d * tj[j];
    }
    out[b * FF + tid] = tanhf(acc);
}

extern "C" void kernel_launch(void* const* d_in, const int* in_sizes, int n_in,
                              void* d_out, int out_size, void* d_ws, size_t ws_size,
                              hipStream_t stream) {
    const float* x     = (const float*)d_in[0];
    const float* cw    = (const float*)d_in[1];
    const float* cb    = (const float*)d_in[2];
    const float* tlw   = (const float*)d_in[3];
    const float* tlb   = (const float*)d_in[4];
    const float* ta    = (const float*)d_in[5];
    const float* tbias = (const float*)d_in[6];
    const float* flw   = (const float*)d_in[7];
    const float* flb   = (const float*)d_in[8];
    const float* fa    = (const float*)d_in[9];
    const float* fbias = (const float*)d_in[10];
    const float* emb   = (const float*)d_in[11];
    const float* fcw   = (const float*)d_in[12];
    const float* fcb   = (const float*)d_in[13];
    float* out = (float*)d_out;
    float* ws = (float*)d_ws;

    float* x2   = ws + 409600;
    float* x3T  = ws + 819200;
    float* L    = ws + 1228800;   // reused as Lf
    float* Rt   = ws + 2048000;   // reused as RfT
    float* x4T  = ws + 2867200;
    float* wt   = ws + 3297280;
    float* tlwT = ws + 3411968;
    float* flwT = ws + 3477504;

    int ntile = (WW + TW - 1) / TW;  // 9
    k_prep<<<448, 256, 0, stream>>>(cw, tlw, flw, wt, tlwT, flwT);
    k_conv<<<BB * ntile, 512, 0, stream>>>(x, wt, cb, x2);
    k_lr_t<<<BB * (WW / ITT), 256, 0, stream>>>(x2, tlwT, tlb, L, Rt);
    k_att_t<<<BB * WW, 128, 0, stream>>>(L, Rt, ta, tbias, x2, x3T);
    k_lr_f<<<BB * (FF / ITT), 256, 0, stream>>>(x3T, flwT, flb, L, Rt);
    k_att_f<<<BB * FF, 128, 0, stream>>>(L, Rt, fa, fbias, x3T, x4T);
    k_fc<<<BB, 128, 0, stream>>>(x4T, fcw, emb, fcb, out);
}